// Round 5
// baseline (557.427 us; speedup 1.0000x reference)
//
#include <hip/hip_runtime.h>
#include <hip/hip_bf16.h>
#include <math.h>

#define DIM 256
#define B_SEG 512
#define LN_EPS 1e-5f
#define CHUNK 64    // nodes per block in segsum
#define BM 64       // nodes per tile in gate kernel

typedef __attribute__((ext_vector_type(8))) short bf16x8;
typedef __attribute__((ext_vector_type(4))) float f32x4;

__device__ __forceinline__ float gelu_exact(float v) {
    return 0.5f * v * (1.0f + erff(v * 0.70710678118654752f));
}

__device__ __forceinline__ unsigned int pack2bf(float a, float b) {
    unsigned int ua = (unsigned int)__bfloat16_as_ushort(__float2bfloat16(a));
    unsigned int ub = (unsigned int)__bfloat16_as_ushort(__float2bfloat16(b));
    return ua | (ub << 16);
}

// ---- Kernel 0: Wg top half -> Wt2, k-chunk-major: Wt2[(k>>3)*2048 + c*8 + (k&7)]
// so a B-fragment load (8 consecutive k for one col c) is one contiguous bf16x8,
// and 16 consecutive lanes (c) form a 256B coalesced segment.
__global__ __launch_bounds__(256) void k_wprep(const float* __restrict__ Wg,
                                               __hip_bfloat16* __restrict__ Wt2) {
    int k = blockIdx.x;   // 0..255 (input k row)
    int c = threadIdx.x;  // 0..255 (output col)
    Wt2[((size_t)(k >> 3) << 11) + (c << 3) + (k & 7)] = __float2bfloat16(Wg[(size_t)k * DIM + c]);
}

// ---------------- Kernel 1: segment sum + counts (batch sorted, float4) -------
__global__ __launch_bounds__(256) void k_segsum(const float* __restrict__ x,
                                                const int* __restrict__ batch,
                                                float* __restrict__ sums,  // [B,D]
                                                float* __restrict__ cnt,   // [B]
                                                int n) {
    int i0 = blockIdx.x * CHUNK;
    if (i0 >= n) return;
    int i1 = min(i0 + CHUNK, n);
    const int t  = threadIdx.x;
    const int d4 = (t & 63) * 4;   // dim base (float4)
    const int rg = t >> 6;         // row group 0..3

    float4 acc = make_float4(0.f, 0.f, 0.f, 0.f);
    int cur = -1;
    int run = 0;
    for (int i = i0 + rg; i < i1; i += 4) {
        int b = batch[i];
        if (b != cur) {
            if (cur >= 0) {
                atomicAdd(&sums[(size_t)cur * DIM + d4 + 0], acc.x);
                atomicAdd(&sums[(size_t)cur * DIM + d4 + 1], acc.y);
                atomicAdd(&sums[(size_t)cur * DIM + d4 + 2], acc.z);
                atomicAdd(&sums[(size_t)cur * DIM + d4 + 3], acc.w);
                if (d4 == 0) atomicAdd(&cnt[cur], (float)run);
            }
            acc = make_float4(0.f, 0.f, 0.f, 0.f);
            run = 0; cur = b;
        }
        float4 v = *(const float4*)(x + (size_t)i * DIM + d4);
        acc.x += v.x; acc.y += v.y; acc.z += v.z; acc.w += v.w;
        run++;
    }
    if (cur >= 0) {
        atomicAdd(&sums[(size_t)cur * DIM + d4 + 0], acc.x);
        atomicAdd(&sums[(size_t)cur * DIM + d4 + 1], acc.y);
        atomicAdd(&sums[(size_t)cur * DIM + d4 + 2], acc.z);
        atomicAdd(&sums[(size_t)cur * DIM + d4 + 3], acc.w);
        if (d4 == 0) atomicAdd(&cnt[cur], (float)run);
    }
}

// ---------------- Kernel 2: per-segment VN pipeline (4-way split dots) --------
__global__ __launch_bounds__(256) void k_vn(const float* __restrict__ sums,
                                            const float* __restrict__ cnt,
                                            const float* __restrict__ vn_embed,
                                            const float* __restrict__ W1, const float* __restrict__ b1,
                                            const float* __restrict__ g1, const float* __restrict__ be1,
                                            const float* __restrict__ W2, const float* __restrict__ b2,
                                            const float* __restrict__ g2, const float* __restrict__ be2,
                                            const float* __restrict__ Wg, const float* __restrict__ bg,
                                            float* __restrict__ vn_state_out, // [B,D]
                                            float* __restrict__ nu,           // ws [B,D]
                                            float* __restrict__ gpart) {      // ws [B,D]
    __shared__ float sIn[DIM];
    __shared__ float sRed[DIM];
    __shared__ float sRed2[DIM];
    const int b = blockIdx.x;
    const int d = threadIdx.x;

    float c = cnt[b];
    float denom = fmaxf(c, 1.0f);
    sIn[d] = sums[(size_t)b * DIM + d] / denom;
    __syncthreads();

    float h0 = 0.f, h1 = 0.f, h2a = 0.f, h3 = 0.f;
    for (int k = 0; k < DIM; k += 4) {
        h0  = fmaf(sIn[k + 0], W1[(size_t)(k + 0) * DIM + d], h0);
        h1  = fmaf(sIn[k + 1], W1[(size_t)(k + 1) * DIM + d], h1);
        h2a = fmaf(sIn[k + 2], W1[(size_t)(k + 2) * DIM + d], h2a);
        h3  = fmaf(sIn[k + 3], W1[(size_t)(k + 3) * DIM + d], h3);
    }
    float h = gelu_exact(b1[d] + ((h0 + h1) + (h2a + h3)));

    sRed[d] = h; sRed2[d] = h * h;
    __syncthreads();
    for (int s = 128; s > 0; s >>= 1) {
        if (d < s) { sRed[d] += sRed[d + s]; sRed2[d] += sRed2[d + s]; }
        __syncthreads();
    }
    float mu = sRed[0] * (1.0f / DIM);
    float var = fmaxf(sRed2[0] * (1.0f / DIM) - mu * mu, 0.0f);
    float rs = rsqrtf(var + LN_EPS);
    float vnst = vn_embed[d] + ((h - mu) * rs * g1[d] + be1[d]);
    vn_state_out[(size_t)b * DIM + d] = vnst;
    __syncthreads();
    sIn[d] = vnst;
    __syncthreads();

    float g0 = 0.f, g1a = 0.f, g2a = 0.f, g3 = 0.f;
    for (int k = 0; k < DIM; k += 4) {
        g0  = fmaf(sIn[k + 0], W2[(size_t)(k + 0) * DIM + d], g0);
        g1a = fmaf(sIn[k + 1], W2[(size_t)(k + 1) * DIM + d], g1a);
        g2a = fmaf(sIn[k + 2], W2[(size_t)(k + 2) * DIM + d], g2a);
        g3  = fmaf(sIn[k + 3], W2[(size_t)(k + 3) * DIM + d], g3);
    }
    float h2 = gelu_exact(b2[d] + ((g0 + g1a) + (g2a + g3)));

    sRed[d] = h2; sRed2[d] = h2 * h2;
    __syncthreads();
    for (int s = 128; s > 0; s >>= 1) {
        if (d < s) { sRed[d] += sRed[d + s]; sRed2[d] += sRed2[d + s]; }
        __syncthreads();
    }
    float mu2 = sRed[0] * (1.0f / DIM);
    float var2 = fmaxf(sRed2[0] * (1.0f / DIM) - mu2 * mu2, 0.0f);
    float rs2 = rsqrtf(var2 + LN_EPS);
    float nud = (h2 - mu2) * rs2 * g2[d] + be2[d];
    nu[(size_t)b * DIM + d] = nud;
    __syncthreads();
    sIn[d] = nud;
    __syncthreads();

    float p0 = 0.f, p1 = 0.f, p2 = 0.f, p3 = 0.f;
    for (int k = 0; k < DIM; k += 4) {
        p0 = fmaf(sIn[k + 0], Wg[(size_t)(DIM + k + 0) * DIM + d], p0);
        p1 = fmaf(sIn[k + 1], Wg[(size_t)(DIM + k + 1) * DIM + d], p1);
        p2 = fmaf(sIn[k + 2], Wg[(size_t)(DIM + k + 2) * DIM + d], p2);
        p3 = fmaf(sIn[k + 3], Wg[(size_t)(DIM + k + 3) * DIM + d], p3);
    }
    gpart[(size_t)b * DIM + d] = bg[d] + ((p0 + p1) + (p2 + p3));
}

// ---------------- Kernel 3: persistent pipelined MFMA gate GEMM ---------------
// Grid-stride over tiles of BM=64 nodes; double-buffered 32KB LDS A tiles.
// Per tile: issue loads(t+1) -> MFMA(t) -> cvt+ds_write(t+1 -> buf^1)
//           -> epilogue(t, residual from LDS) -> ONE barrier.
// B frags from k-chunk-major Wt2 (L2-resident, coalesced 256B segments).
__global__ __launch_bounds__(256, 2) void k_gate_mfma(const float* __restrict__ x,
                                                      const int* __restrict__ batch,
                                                      const __hip_bfloat16* __restrict__ Wt2,
                                                      const float* __restrict__ nu,    // [B,D]
                                                      const float* __restrict__ gpart, // [B,D]
                                                      float* __restrict__ xout,
                                                      int n, int ntiles) {
    __shared__ __align__(16) char sA[2][BM * 512];   // 2 x 32 KB, [r][k] bf16 swizzled

    const int tid  = threadIdx.x;
    const int wave = tid >> 6;
    const int lane = tid & 63;
    const int r15  = lane & 15;
    const int kq   = lane >> 4;      // 0..3 : k-subgroup (8 elems)
    const int stride = gridDim.x;

    float4 av0[8], av1[8];

    auto loadT = [&](int tile) {
        const int i0 = tile * BM;
        #pragma unroll
        for (int j = 0; j < 8; ++j) {
            int v = j * 256 + tid;       // 0..2047
            int r = v >> 5;              // row 0..63
            int k8 = v & 31;             // 8-float k-group
            int node = i0 + r;
            if (node < n) {
                const float* p = x + (size_t)node * DIM + k8 * 8;
                av0[j] = *(const float4*)p;
                av1[j] = *(const float4*)(p + 4);
            } else {
                av0[j] = make_float4(0.f, 0.f, 0.f, 0.f);
                av1[j] = av0[j];
            }
        }
    };
    auto writeT = [&](int buf) {
        #pragma unroll
        for (int j = 0; j < 8; ++j) {
            int v = j * 256 + tid;
            int r = v >> 5;
            int k8 = v & 31;
            uint4 pk;
            pk.x = pack2bf(av0[j].x, av0[j].y);
            pk.y = pack2bf(av0[j].z, av0[j].w);
            pk.z = pack2bf(av1[j].x, av1[j].y);
            pk.w = pack2bf(av1[j].z, av1[j].w);
            *(uint4*)(&sA[buf][0] + r * 512 + ((k8 * 16) ^ ((r & 7) << 4))) = pk;
        }
    };

    int tile = blockIdx.x;
    if (tile >= ntiles) return;

    loadT(tile);
    writeT(0);
    __syncthreads();
    int buf = 0;

    for (; tile < ntiles; tile += stride) {
        const int nxt = tile + stride;
        const bool hasNext = nxt < ntiles;
        if (hasNext) loadT(nxt);           // HBM reads in flight across this tile

        f32x4 acc[4][4];
        #pragma unroll
        for (int m = 0; m < 4; ++m)
            #pragma unroll
            for (int nn = 0; nn < 4; ++nn)
                acc[m][nn] = (f32x4){0.f, 0.f, 0.f, 0.f};

        const char* sAb = &sA[buf][0];
        #pragma unroll
        for (int ks = 0; ks < 8; ++ks) {
            bf16x8 a[4], b[4];
            #pragma unroll
            for (int nn = 0; nn < 4; ++nn) {
                int c = wave * 64 + nn * 16 + r15;
                b[nn] = *(const bf16x8*)(Wt2 + ((size_t)(ks * 4 + kq) << 11) + (c << 3));
            }
            #pragma unroll
            for (int m = 0; m < 4; ++m) {
                int r = m * 16 + r15;
                a[m] = *(const bf16x8*)(sAb + r * 512 + ((ks * 64 + kq * 16) ^ ((r & 7) << 4)));
            }
            #pragma unroll
            for (int m = 0; m < 4; ++m)
                #pragma unroll
                for (int nn = 0; nn < 4; ++nn)
                    acc[m][nn] = __builtin_amdgcn_mfma_f32_16x16x32_bf16(a[m], b[nn], acc[m][nn], 0, 0, 0);
        }

        if (hasNext) writeT(buf ^ 1);      // vmcnt wait lands here (the BW limit)

        // epilogue: + gpart[seg], sigmoid, residual(from LDS bf16) + g*nu
        const int i0 = tile * BM;
        #pragma unroll
        for (int m = 0; m < 4; ++m) {
            #pragma unroll
            for (int q = 0; q < 4; ++q) {
                int rr = m * 16 + kq * 4 + q;
                int node = i0 + rr;
                if (node >= n) continue;
                int bb = batch[node];
                #pragma unroll
                for (int nn = 0; nn < 4; ++nn) {
                    int col = wave * 64 + nn * 16 + r15;
                    float pre = acc[m][nn][q] + gpart[bb * DIM + col];
                    float e = __expf(-pre);
                    float gte = __builtin_amdgcn_rcpf(1.0f + e);
                    float xres = __bfloat162float(
                        *(const __hip_bfloat16*)(sAb + rr * 512 + ((2 * col) ^ ((rr & 7) << 4))));
                    xout[(size_t)node * DIM + col] = xres + gte * nu[bb * DIM + col];
                }
            }
        }
        __syncthreads();
        buf ^= 1;
    }
}

extern "C" void kernel_launch(void* const* d_in, const int* in_sizes, int n_in,
                              void* d_out, int out_size, void* d_ws, size_t ws_size,
                              hipStream_t stream) {
    const float* x        = (const float*)d_in[0];
    const int*   batch    = (const int*)d_in[1];
    const float* vn_embed = (const float*)d_in[2];
    const float* W1  = (const float*)d_in[3];
    const float* b1  = (const float*)d_in[4];
    const float* g1  = (const float*)d_in[5];
    const float* be1 = (const float*)d_in[6];
    const float* W2  = (const float*)d_in[7];
    const float* b2  = (const float*)d_in[8];
    const float* g2  = (const float*)d_in[9];
    const float* be2 = (const float*)d_in[10];
    const float* Wg  = (const float*)d_in[11];
    const float* bg  = (const float*)d_in[12];

    const int n = in_sizes[0] / DIM;

    float* out = (float*)d_out;
    float* xout = out;                              // [N,D]
    float* vn_state_out = out + (size_t)n * DIM;    // [B,D]

    float* ws    = (float*)d_ws;
    float* sums  = ws;                                   // B*D
    float* cnt   = sums + (size_t)B_SEG * DIM;           // B
    float* nu    = cnt + B_SEG;                          // B*D
    float* gpart = nu + (size_t)B_SEG * DIM;             // B*D
    __hip_bfloat16* Wt2 = (__hip_bfloat16*)(gpart + (size_t)B_SEG * DIM); // 256*256 bf16

    hipMemsetAsync(d_ws, 0, ((size_t)B_SEG * DIM + B_SEG) * sizeof(float), stream);

    k_wprep<<<DIM, DIM, 0, stream>>>(Wg, Wt2);

    int nblk1 = (n + CHUNK - 1) / CHUNK;
    k_segsum<<<nblk1, 256, 0, stream>>>(x, batch, sums, cnt, n);

    k_vn<<<B_SEG, 256, 0, stream>>>(sums, cnt, vn_embed,
                                    W1, b1, g1, be1,
                                    W2, b2, g2, be2,
                                    Wg, bg,
                                    vn_state_out, nu, gpart);

    const int ntiles = (n + BM - 1) / BM;
    int nblk3 = (ntiles <= 2048) ? ntiles : (ntiles + 2) / 3;
    k_gate_mfma<<<nblk3, 256, 0, stream>>>(x, batch, Wt2, nu, gpart, xout, n, ntiles);
}

// Round 6
// 229.364 us; speedup vs baseline: 2.4303x; 2.4303x over previous
//
#include <hip/hip_runtime.h>
#include <hip/hip_bf16.h>
#include <math.h>

#define DIM 256
#define B_SEG 512
#define LN_EPS 1e-5f
#define CHUNK 64    // nodes per block in segsum

typedef __attribute__((ext_vector_type(8))) short bf16x8;
typedef __attribute__((ext_vector_type(4))) float f32x4;

__device__ __forceinline__ float gelu_exact(float v) {
    return 0.5f * v * (1.0f + erff(v * 0.70710678118654752f));
}

__device__ __forceinline__ unsigned int pack2bf(float a, float b) {
    unsigned int ua = (unsigned int)__bfloat16_as_ushort(__float2bfloat16(a));
    unsigned int ub = (unsigned int)__bfloat16_as_ushort(__float2bfloat16(b));
    return ua | (ub << 16);
}

__device__ __forceinline__ void async16(const void* g, void* l) {
    __builtin_amdgcn_global_load_lds(
        (const __attribute__((address_space(1))) void*)(g),
        (__attribute__((address_space(3))) void*)(l), 16, 0, 0);
}

// ---- Kernel 0: Wg top half -> Wt2, k-chunk-major: Wt2[(k>>3)*2048 + c*8 + (k&7)]
__global__ __launch_bounds__(256) void k_wprep(const float* __restrict__ Wg,
                                               __hip_bfloat16* __restrict__ Wt2) {
    int k = blockIdx.x;   // 0..255 (input k row)
    int c = threadIdx.x;  // 0..255 (output col)
    Wt2[((size_t)(k >> 3) << 11) + (c << 3) + (k & 7)] = __float2bfloat16(Wg[(size_t)k * DIM + c]);
}

// ---- Kernel 1: segment sum + counts; optionally emits pre-swizzled bf16 x ----
// xbf row layout: byte pos of k-elems [k..k+4) = (2k) ^ ((row&7)<<4)  (8B stores)
__global__ __launch_bounds__(256) void k_segsum(const float* __restrict__ x,
                                                const int* __restrict__ batch,
                                                float* __restrict__ sums,  // [B,D]
                                                float* __restrict__ cnt,   // [B]
                                                __hip_bfloat16* __restrict__ xbf,
                                                int n, int emit) {
    int i0 = blockIdx.x * CHUNK;
    if (i0 >= n) return;
    int i1 = min(i0 + CHUNK, n);
    const int t    = threadIdx.x;
    const int lane = t & 63;
    const int d4   = lane * 4;     // dim base (float4)
    const int rg   = t >> 6;       // row group 0..3 (= wave)

    float4 acc = make_float4(0.f, 0.f, 0.f, 0.f);
    int cur = -1;
    int run = 0;
    for (int i = i0 + rg; i < i1; i += 4) {
        int b = batch[i];
        if (b != cur) {
            if (cur >= 0) {
                atomicAdd(&sums[(size_t)cur * DIM + d4 + 0], acc.x);
                atomicAdd(&sums[(size_t)cur * DIM + d4 + 1], acc.y);
                atomicAdd(&sums[(size_t)cur * DIM + d4 + 2], acc.z);
                atomicAdd(&sums[(size_t)cur * DIM + d4 + 3], acc.w);
                if (d4 == 0) atomicAdd(&cnt[cur], (float)run);
            }
            acc = make_float4(0.f, 0.f, 0.f, 0.f);
            run = 0; cur = b;
        }
        float4 v = *(const float4*)(x + (size_t)i * DIM + d4);
        if (emit) {
            uint2 pk;
            pk.x = pack2bf(v.x, v.y);
            pk.y = pack2bf(v.z, v.w);
            *(uint2*)((char*)xbf + (size_t)i * 512 + ((d4 * 2) ^ ((i & 7) << 4))) = pk;
        }
        acc.x += v.x; acc.y += v.y; acc.z += v.z; acc.w += v.w;
        run++;
    }
    if (cur >= 0) {
        atomicAdd(&sums[(size_t)cur * DIM + d4 + 0], acc.x);
        atomicAdd(&sums[(size_t)cur * DIM + d4 + 1], acc.y);
        atomicAdd(&sums[(size_t)cur * DIM + d4 + 2], acc.z);
        atomicAdd(&sums[(size_t)cur * DIM + d4 + 3], acc.w);
        if (d4 == 0) atomicAdd(&cnt[cur], (float)run);
    }
}

// ---------------- Kernel 2: per-segment VN pipeline (4-way split dots) --------
__global__ __launch_bounds__(256) void k_vn(const float* __restrict__ sums,
                                            const float* __restrict__ cnt,
                                            const float* __restrict__ vn_embed,
                                            const float* __restrict__ W1, const float* __restrict__ b1,
                                            const float* __restrict__ g1, const float* __restrict__ be1,
                                            const float* __restrict__ W2, const float* __restrict__ b2,
                                            const float* __restrict__ g2, const float* __restrict__ be2,
                                            const float* __restrict__ Wg, const float* __restrict__ bg,
                                            float* __restrict__ vn_state_out, // [B,D]
                                            float* __restrict__ nu,           // ws [B,D]
                                            float* __restrict__ gpart) {      // ws [B,D]
    __shared__ float sIn[DIM];
    __shared__ float sRed[DIM];
    __shared__ float sRed2[DIM];
    const int b = blockIdx.x;
    const int d = threadIdx.x;

    float c = cnt[b];
    float denom = fmaxf(c, 1.0f);
    sIn[d] = sums[(size_t)b * DIM + d] / denom;
    __syncthreads();

    float h0 = 0.f, h1 = 0.f, h2a = 0.f, h3 = 0.f;
    for (int k = 0; k < DIM; k += 4) {
        h0  = fmaf(sIn[k + 0], W1[(size_t)(k + 0) * DIM + d], h0);
        h1  = fmaf(sIn[k + 1], W1[(size_t)(k + 1) * DIM + d], h1);
        h2a = fmaf(sIn[k + 2], W1[(size_t)(k + 2) * DIM + d], h2a);
        h3  = fmaf(sIn[k + 3], W1[(size_t)(k + 3) * DIM + d], h3);
    }
    float h = gelu_exact(b1[d] + ((h0 + h1) + (h2a + h3)));

    sRed[d] = h; sRed2[d] = h * h;
    __syncthreads();
    for (int s = 128; s > 0; s >>= 1) {
        if (d < s) { sRed[d] += sRed[d + s]; sRed2[d] += sRed2[d + s]; }
        __syncthreads();
    }
    float mu = sRed[0] * (1.0f / DIM);
    float var = fmaxf(sRed2[0] * (1.0f / DIM) - mu * mu, 0.0f);
    float rs = rsqrtf(var + LN_EPS);
    float vnst = vn_embed[d] + ((h - mu) * rs * g1[d] + be1[d]);
    vn_state_out[(size_t)b * DIM + d] = vnst;
    __syncthreads();
    sIn[d] = vnst;
    __syncthreads();

    float g0 = 0.f, g1a = 0.f, g2a = 0.f, g3 = 0.f;
    for (int k = 0; k < DIM; k += 4) {
        g0  = fmaf(sIn[k + 0], W2[(size_t)(k + 0) * DIM + d], g0);
        g1a = fmaf(sIn[k + 1], W2[(size_t)(k + 1) * DIM + d], g1a);
        g2a = fmaf(sIn[k + 2], W2[(size_t)(k + 2) * DIM + d], g2a);
        g3  = fmaf(sIn[k + 3], W2[(size_t)(k + 3) * DIM + d], g3);
    }
    float h2 = gelu_exact(b2[d] + ((g0 + g1a) + (g2a + g3)));

    sRed[d] = h2; sRed2[d] = h2 * h2;
    __syncthreads();
    for (int s = 128; s > 0; s >>= 1) {
        if (d < s) { sRed[d] += sRed[d + s]; sRed2[d] += sRed2[d + s]; }
        __syncthreads();
    }
    float mu2 = sRed[0] * (1.0f / DIM);
    float var2 = fmaxf(sRed2[0] * (1.0f / DIM) - mu2 * mu2, 0.0f);
    float rs2 = rsqrtf(var2 + LN_EPS);
    float nud = (h2 - mu2) * rs2 * g2[d] + be2[d];
    nu[(size_t)b * DIM + d] = nud;
    __syncthreads();
    sIn[d] = nud;
    __syncthreads();

    float p0 = 0.f, p1 = 0.f, p2 = 0.f, p3 = 0.f;
    for (int k = 0; k < DIM; k += 4) {
        p0 = fmaf(sIn[k + 0], Wg[(size_t)(DIM + k + 0) * DIM + d], p0);
        p1 = fmaf(sIn[k + 1], Wg[(size_t)(DIM + k + 1) * DIM + d], p1);
        p2 = fmaf(sIn[k + 2], Wg[(size_t)(DIM + k + 2) * DIM + d], p2);
        p3 = fmaf(sIn[k + 3], Wg[(size_t)(DIM + k + 3) * DIM + d], p3);
    }
    gpart[(size_t)b * DIM + d] = bg[d] + ((p0 + p1) + (p2 + p3));
}

// ---- Kernel 3a (bf16 path): gate GEMM, A via global_load_lds from xbf --------
// BM=64, 256 threads = 4 waves; ~no staging registers -> 5 blocks/CU (LDS-bound)
__global__ __launch_bounds__(256, 4) void k_gate_bf(const __hip_bfloat16* __restrict__ xbf,
                                                    const int* __restrict__ batch,
                                                    const __hip_bfloat16* __restrict__ Wt2,
                                                    const float* __restrict__ nu,    // [B,D]
                                                    const float* __restrict__ gpart, // [B,D]
                                                    float* __restrict__ xout,
                                                    int n) {
    __shared__ __align__(16) char sA[64 * 512];   // 32 KB, pre-swizzled rows

    const int tid  = threadIdx.x;
    const int wave = tid >> 6;
    const int lane = tid & 63;
    const int r15  = lane & 15;
    const int kq   = lane >> 4;
    const size_t i0 = (size_t)blockIdx.x * 64;

    // stage: 8 x 16B async copies per thread; LDS dest wave-uniform base (m104)
    const char* gsrc = (const char*)xbf + i0 * 512;
    #pragma unroll
    for (int j = 0; j < 8; ++j)
        async16(gsrc + j * 4096 + tid * 16, sA + j * 4096 + wave * 1024);
    __syncthreads();   // compiler inserts vmcnt(0) drain here

    f32x4 acc[4][4];
    #pragma unroll
    for (int m = 0; m < 4; ++m)
        #pragma unroll
        for (int nn = 0; nn < 4; ++nn)
            acc[m][nn] = (f32x4){0.f, 0.f, 0.f, 0.f};

    #pragma unroll
    for (int ks = 0; ks < 8; ++ks) {
        bf16x8 a[4], b[4];
        #pragma unroll
        for (int nn = 0; nn < 4; ++nn) {
            int c = wave * 64 + nn * 16 + r15;
            b[nn] = *(const bf16x8*)(Wt2 + ((size_t)(ks * 4 + kq) << 11) + (c << 3));
        }
        #pragma unroll
        for (int m = 0; m < 4; ++m) {
            int r = m * 16 + r15;
            a[m] = *(const bf16x8*)(sA + r * 512 + ((ks * 64 + kq * 16) ^ ((r & 7) << 4)));
        }
        #pragma unroll
        for (int m = 0; m < 4; ++m)
            #pragma unroll
            for (int nn = 0; nn < 4; ++nn)
                acc[m][nn] = __builtin_amdgcn_mfma_f32_16x16x32_bf16(a[m], b[nn], acc[m][nn], 0, 0, 0);
    }

    // epilogue: + gpart[seg], sigmoid, residual (LDS bf16) + g*nu
    #pragma unroll
    for (int m = 0; m < 4; ++m) {
        #pragma unroll
        for (int q = 0; q < 4; ++q) {
            int rr = m * 16 + kq * 4 + q;
            long node = (long)(i0 + rr);
            if (node >= n) continue;
            int bb = batch[node];
            #pragma unroll
            for (int nn = 0; nn < 4; ++nn) {
                int col = wave * 64 + nn * 16 + r15;
                float pre = acc[m][nn][q] + gpart[bb * DIM + col];
                float e = __expf(-pre);
                float gte = __builtin_amdgcn_rcpf(1.0f + e);
                float xres = __bfloat162float(
                    *(const __hip_bfloat16*)(sA + rr * 512 + ((2 * col) ^ ((rr & 7) << 4))));
                xout[(size_t)node * DIM + col] = xres + gte * nu[bb * DIM + col];
            }
        }
    }
}

// ---- Kernel 3b (fp32 fallback): reg-staged, BM=32 for high occupancy ---------
__global__ __launch_bounds__(256) void k_gate_fp(const float* __restrict__ x,
                                                 const int* __restrict__ batch,
                                                 const __hip_bfloat16* __restrict__ Wt2,
                                                 const float* __restrict__ nu,
                                                 const float* __restrict__ gpart,
                                                 float* __restrict__ xout,
                                                 int n) {
    __shared__ __align__(16) char sA[32 * 512];   // 16 KB bf16, swizzled

    const int tid  = threadIdx.x;
    const int wave = tid >> 6;
    const int lane = tid & 63;
    const int r15  = lane & 15;
    const int kq   = lane >> 4;
    const int i0   = blockIdx.x * 32;

    float4 av0[4], av1[4];
    #pragma unroll
    for (int j = 0; j < 4; ++j) {
        int v = j * 256 + tid;       // 0..1023
        int r = v >> 5;              // row 0..31
        int k8 = v & 31;
        int node = i0 + r;
        if (node < n) {
            const float* p = x + (size_t)node * DIM + k8 * 8;
            av0[j] = *(const float4*)p;
            av1[j] = *(const float4*)(p + 4);
        } else {
            av0[j] = make_float4(0.f, 0.f, 0.f, 0.f);
            av1[j] = av0[j];
        }
    }
    #pragma unroll
    for (int j = 0; j < 4; ++j) {
        int v = j * 256 + tid;
        int r = v >> 5;
        int k8 = v & 31;
        uint4 pk;
        pk.x = pack2bf(av0[j].x, av0[j].y);
        pk.y = pack2bf(av0[j].z, av0[j].w);
        pk.z = pack2bf(av1[j].x, av1[j].y);
        pk.w = pack2bf(av1[j].z, av1[j].w);
        *(uint4*)(sA + r * 512 + ((k8 * 16) ^ ((r & 7) << 4))) = pk;
    }
    __syncthreads();

    f32x4 acc[2][4];
    #pragma unroll
    for (int m = 0; m < 2; ++m)
        #pragma unroll
        for (int nn = 0; nn < 4; ++nn)
            acc[m][nn] = (f32x4){0.f, 0.f, 0.f, 0.f};

    #pragma unroll
    for (int ks = 0; ks < 8; ++ks) {
        bf16x8 a[2], b[4];
        #pragma unroll
        for (int nn = 0; nn < 4; ++nn) {
            int c = wave * 64 + nn * 16 + r15;
            b[nn] = *(const bf16x8*)(Wt2 + ((size_t)(ks * 4 + kq) << 11) + (c << 3));
        }
        #pragma unroll
        for (int m = 0; m < 2; ++m) {
            int r = m * 16 + r15;
            a[m] = *(const bf16x8*)(sA + r * 512 + ((ks * 64 + kq * 16) ^ ((r & 7) << 4)));
        }
        #pragma unroll
        for (int m = 0; m < 2; ++m)
            #pragma unroll
            for (int nn = 0; nn < 4; ++nn)
                acc[m][nn] = __builtin_amdgcn_mfma_f32_16x16x32_bf16(a[m], b[nn], acc[m][nn], 0, 0, 0);
    }

    #pragma unroll
    for (int m = 0; m < 2; ++m) {
        #pragma unroll
        for (int q = 0; q < 4; ++q) {
            int rr = m * 16 + kq * 4 + q;
            int node = i0 + rr;
            if (node >= n) continue;
            int bb = batch[node];
            #pragma unroll
            for (int nn = 0; nn < 4; ++nn) {
                int col = wave * 64 + nn * 16 + r15;
                float pre = acc[m][nn][q] + gpart[bb * DIM + col];
                float e = __expf(-pre);
                float gte = __builtin_amdgcn_rcpf(1.0f + e);
                float xres = __bfloat162float(
                    *(const __hip_bfloat16*)(sA + rr * 512 + ((2 * col) ^ ((rr & 7) << 4))));
                xout[(size_t)node * DIM + col] = xres + gte * nu[bb * DIM + col];
            }
        }
    }
}

extern "C" void kernel_launch(void* const* d_in, const int* in_sizes, int n_in,
                              void* d_out, int out_size, void* d_ws, size_t ws_size,
                              hipStream_t stream) {
    const float* x        = (const float*)d_in[0];
    const int*   batch    = (const int*)d_in[1];
    const float* vn_embed = (const float*)d_in[2];
    const float* W1  = (const float*)d_in[3];
    const float* b1  = (const float*)d_in[4];
    const float* g1  = (const float*)d_in[5];
    const float* be1 = (const float*)d_in[6];
    const float* W2  = (const float*)d_in[7];
    const float* b2  = (const float*)d_in[8];
    const float* g2  = (const float*)d_in[9];
    const float* be2 = (const float*)d_in[10];
    const float* Wg  = (const float*)d_in[11];
    const float* bg  = (const float*)d_in[12];

    const int n = in_sizes[0] / DIM;

    float* out = (float*)d_out;
    float* xout = out;                              // [N,D]
    float* vn_state_out = out + (size_t)n * DIM;    // [B,D]

    float* ws    = (float*)d_ws;
    float* sums  = ws;                                   // B*D
    float* cnt   = sums + (size_t)B_SEG * DIM;           // B
    float* nu    = cnt + B_SEG;                          // B*D
    float* gpart = nu + (size_t)B_SEG * DIM;             // B*D
    __hip_bfloat16* Wt2 = (__hip_bfloat16*)(gpart + (size_t)B_SEG * DIM); // 64K bf16
    __hip_bfloat16* xbf = Wt2 + (size_t)DIM * DIM;       // [ntile64*64][256] bf16

    const size_t base_bytes = ((size_t)B_SEG * DIM * 3 + B_SEG) * 4 + (size_t)DIM * DIM * 2;
    const int nt64 = (n + 63) / 64;
    const size_t need = base_bytes + (size_t)nt64 * 64 * 512;
    const bool use_bf = (ws_size >= need);

    hipMemsetAsync(d_ws, 0, ((size_t)B_SEG * DIM + B_SEG) * sizeof(float), stream);

    k_wprep<<<DIM, DIM, 0, stream>>>(Wg, Wt2);

    int nblk1 = (n + CHUNK - 1) / CHUNK;
    k_segsum<<<nblk1, 256, 0, stream>>>(x, batch, sums, cnt, xbf, n, use_bf ? 1 : 0);

    k_vn<<<B_SEG, 256, 0, stream>>>(sums, cnt, vn_embed,
                                    W1, b1, g1, be1,
                                    W2, b2, g2, be2,
                                    Wg, bg,
                                    vn_state_out, nu, gpart);

    if (use_bf) {
        k_gate_bf<<<nt64, 256, 0, stream>>>(xbf, batch, Wt2, nu, gpart, xout, n);
    } else {
        int nblk3 = (n + 31) / 32;
        k_gate_fp<<<nblk3, 256, 0, stream>>>(x, batch, Wt2, nu, gpart, xout, n);
    }
}

// Round 7
// 220.058 us; speedup vs baseline: 2.5331x; 1.0423x over previous
//
#include <hip/hip_runtime.h>
#include <hip/hip_bf16.h>
#include <math.h>

#define DIM 256
#define B_SEG 512
#define LN_EPS 1e-5f
#define CHUNK 64    // nodes per block in segsum

typedef __attribute__((ext_vector_type(8))) short bf16x8;
typedef __attribute__((ext_vector_type(4))) float f32x4;

__device__ __forceinline__ float gelu_exact(float v) {
    return 0.5f * v * (1.0f + erff(v * 0.70710678118654752f));
}

__device__ __forceinline__ unsigned int pack2bf(float a, float b) {
    unsigned int ua = (unsigned int)__bfloat16_as_ushort(__float2bfloat16(a));
    unsigned int ub = (unsigned int)__bfloat16_as_ushort(__float2bfloat16(b));
    return ua | (ub << 16);
}

__device__ __forceinline__ void async16(const void* g, void* l) {
    __builtin_amdgcn_global_load_lds(
        (const __attribute__((address_space(1))) void*)(g),
        (__attribute__((address_space(3))) void*)(l), 16, 0, 0);
}

// ---- Kernel 0: Wg top half -> Wt2, k-chunk-major: Wt2[(k>>3)*2048 + c*8 + (k&7)]
__global__ __launch_bounds__(256) void k_wprep(const float* __restrict__ Wg,
                                               __hip_bfloat16* __restrict__ Wt2) {
    int k = blockIdx.x;   // 0..255 (input k row)
    int c = threadIdx.x;  // 0..255 (output col)
    Wt2[((size_t)(k >> 3) << 11) + (c << 3) + (k & 7)] = __float2bfloat16(Wg[(size_t)k * DIM + c]);
}

// ---- Kernel 1: segment sum + counts + pre-swizzled bf16 emit, phase-split ----
// Phase 1: all loads issued up-front (16 float4 + 16 batch ids, independent).
// Phase 2: emit swizzled bf16 copy (independent stores).
// Phase 3: in-register boundary scan (wave-uniform branches), rare atomics.
__global__ __launch_bounds__(256) void k_segsum(const float* __restrict__ x,
                                                const int* __restrict__ batch,
                                                float* __restrict__ sums,  // [B,D]
                                                float* __restrict__ cnt,   // [B]
                                                __hip_bfloat16* __restrict__ xbf,
                                                int n, int emit) {
    const int i0 = blockIdx.x * CHUNK;
    if (i0 >= n) return;
    const int t    = threadIdx.x;
    const int lane = t & 63;
    const int d4   = lane * 4;     // dim base (float4)
    const int rg   = t >> 6;       // row group 0..3 (= wave)

    // ---- phase 1: issue ALL loads ----
    int   bt[16];
    float4 v[16];
    #pragma unroll
    for (int j = 0; j < 16; ++j) {
        int i = i0 + rg + 4 * j;
        bt[j] = (i < n) ? batch[i] : -1;
    }
    #pragma unroll
    for (int j = 0; j < 16; ++j) {
        int i = i0 + rg + 4 * j;
        v[j] = (i < n) ? *(const float4*)(x + (size_t)i * DIM + d4)
                       : make_float4(0.f, 0.f, 0.f, 0.f);
    }

    // ---- phase 2: emit pre-swizzled bf16 copy ----
    if (emit) {
        #pragma unroll
        for (int j = 0; j < 16; ++j) {
            int i = i0 + rg + 4 * j;
            if (i < n) {
                uint2 pk;
                pk.x = pack2bf(v[j].x, v[j].y);
                pk.y = pack2bf(v[j].z, v[j].w);
                *(uint2*)((char*)xbf + (size_t)i * 512 + ((d4 * 2) ^ ((i & 7) << 4))) = pk;
            }
        }
    }

    // ---- phase 3: in-register scan (branches wave-uniform: bt same per wave) ----
    float4 acc = make_float4(0.f, 0.f, 0.f, 0.f);
    int cur = -1, run = 0;
    #pragma unroll
    for (int j = 0; j < 16; ++j) {
        if (bt[j] != cur) {
            if (cur >= 0) {
                atomicAdd(&sums[(size_t)cur * DIM + d4 + 0], acc.x);
                atomicAdd(&sums[(size_t)cur * DIM + d4 + 1], acc.y);
                atomicAdd(&sums[(size_t)cur * DIM + d4 + 2], acc.z);
                atomicAdd(&sums[(size_t)cur * DIM + d4 + 3], acc.w);
                if (d4 == 0) atomicAdd(&cnt[cur], (float)run);
            }
            acc = make_float4(0.f, 0.f, 0.f, 0.f);
            run = 0; cur = bt[j];
        }
        acc.x += v[j].x; acc.y += v[j].y; acc.z += v[j].z; acc.w += v[j].w;
        run++;
    }
    if (cur >= 0) {
        atomicAdd(&sums[(size_t)cur * DIM + d4 + 0], acc.x);
        atomicAdd(&sums[(size_t)cur * DIM + d4 + 1], acc.y);
        atomicAdd(&sums[(size_t)cur * DIM + d4 + 2], acc.z);
        atomicAdd(&sums[(size_t)cur * DIM + d4 + 3], acc.w);
        if (d4 == 0) atomicAdd(&cnt[cur], (float)run);
    }
}

// ---------------- Kernel 2: per-segment VN pipeline (4-way split dots) --------
__global__ __launch_bounds__(256) void k_vn(const float* __restrict__ sums,
                                            const float* __restrict__ cnt,
                                            const float* __restrict__ vn_embed,
                                            const float* __restrict__ W1, const float* __restrict__ b1,
                                            const float* __restrict__ g1, const float* __restrict__ be1,
                                            const float* __restrict__ W2, const float* __restrict__ b2,
                                            const float* __restrict__ g2, const float* __restrict__ be2,
                                            const float* __restrict__ Wg, const float* __restrict__ bg,
                                            float* __restrict__ vn_state_out, // [B,D]
                                            float* __restrict__ nu,           // ws [B,D]
                                            float* __restrict__ gpart) {      // ws [B,D]
    __shared__ float sIn[DIM];
    __shared__ float sRed[DIM];
    __shared__ float sRed2[DIM];
    const int b = blockIdx.x;
    const int d = threadIdx.x;

    float c = cnt[b];
    float denom = fmaxf(c, 1.0f);
    sIn[d] = sums[(size_t)b * DIM + d] / denom;
    __syncthreads();

    float h0 = 0.f, h1 = 0.f, h2a = 0.f, h3 = 0.f;
    for (int k = 0; k < DIM; k += 4) {
        h0  = fmaf(sIn[k + 0], W1[(size_t)(k + 0) * DIM + d], h0);
        h1  = fmaf(sIn[k + 1], W1[(size_t)(k + 1) * DIM + d], h1);
        h2a = fmaf(sIn[k + 2], W1[(size_t)(k + 2) * DIM + d], h2a);
        h3  = fmaf(sIn[k + 3], W1[(size_t)(k + 3) * DIM + d], h3);
    }
    float h = gelu_exact(b1[d] + ((h0 + h1) + (h2a + h3)));

    sRed[d] = h; sRed2[d] = h * h;
    __syncthreads();
    for (int s = 128; s > 0; s >>= 1) {
        if (d < s) { sRed[d] += sRed[d + s]; sRed2[d] += sRed2[d + s]; }
        __syncthreads();
    }
    float mu = sRed[0] * (1.0f / DIM);
    float var = fmaxf(sRed2[0] * (1.0f / DIM) - mu * mu, 0.0f);
    float rs = rsqrtf(var + LN_EPS);
    float vnst = vn_embed[d] + ((h - mu) * rs * g1[d] + be1[d]);
    vn_state_out[(size_t)b * DIM + d] = vnst;
    __syncthreads();
    sIn[d] = vnst;
    __syncthreads();

    float g0 = 0.f, g1a = 0.f, g2a = 0.f, g3 = 0.f;
    for (int k = 0; k < DIM; k += 4) {
        g0  = fmaf(sIn[k + 0], W2[(size_t)(k + 0) * DIM + d], g0);
        g1a = fmaf(sIn[k + 1], W2[(size_t)(k + 1) * DIM + d], g1a);
        g2a = fmaf(sIn[k + 2], W2[(size_t)(k + 2) * DIM + d], g2a);
        g3  = fmaf(sIn[k + 3], W2[(size_t)(k + 3) * DIM + d], g3);
    }
    float h2 = gelu_exact(b2[d] + ((g0 + g1a) + (g2a + g3)));

    sRed[d] = h2; sRed2[d] = h2 * h2;
    __syncthreads();
    for (int s = 128; s > 0; s >>= 1) {
        if (d < s) { sRed[d] += sRed[d + s]; sRed2[d] += sRed2[d + s]; }
        __syncthreads();
    }
    float mu2 = sRed[0] * (1.0f / DIM);
    float var2 = fmaxf(sRed2[0] * (1.0f / DIM) - mu2 * mu2, 0.0f);
    float rs2 = rsqrtf(var2 + LN_EPS);
    float nud = (h2 - mu2) * rs2 * g2[d] + be2[d];
    nu[(size_t)b * DIM + d] = nud;
    __syncthreads();
    sIn[d] = nud;
    __syncthreads();

    float p0 = 0.f, p1 = 0.f, p2 = 0.f, p3 = 0.f;
    for (int k = 0; k < DIM; k += 4) {
        p0 = fmaf(sIn[k + 0], Wg[(size_t)(DIM + k + 0) * DIM + d], p0);
        p1 = fmaf(sIn[k + 1], Wg[(size_t)(DIM + k + 1) * DIM + d], p1);
        p2 = fmaf(sIn[k + 2], Wg[(size_t)(DIM + k + 2) * DIM + d], p2);
        p3 = fmaf(sIn[k + 3], Wg[(size_t)(DIM + k + 3) * DIM + d], p3);
    }
    gpart[(size_t)b * DIM + d] = bg[d] + ((p0 + p1) + (p2 + p3));
}

// ---- Kernel 3a (bf16 path): gate GEMM, A via global_load_lds from xbf --------
__global__ __launch_bounds__(256, 4) void k_gate_bf(const __hip_bfloat16* __restrict__ xbf,
                                                    const int* __restrict__ batch,
                                                    const __hip_bfloat16* __restrict__ Wt2,
                                                    const float* __restrict__ nu,    // [B,D]
                                                    const float* __restrict__ gpart, // [B,D]
                                                    float* __restrict__ xout,
                                                    int n) {
    __shared__ __align__(16) char sA[64 * 512];   // 32 KB, pre-swizzled rows

    const int tid  = threadIdx.x;
    const int wave = tid >> 6;
    const int lane = tid & 63;
    const int r15  = lane & 15;
    const int kq   = lane >> 4;
    const size_t i0 = (size_t)blockIdx.x * 64;

    // stage: 8 x 16B async copies per thread; LDS dest wave-uniform base (m104)
    const char* gsrc = (const char*)xbf + i0 * 512;
    #pragma unroll
    for (int j = 0; j < 8; ++j)
        async16(gsrc + j * 4096 + tid * 16, sA + j * 4096 + wave * 1024);
    __syncthreads();   // compiler inserts vmcnt(0) drain here

    f32x4 acc[4][4];
    #pragma unroll
    for (int m = 0; m < 4; ++m)
        #pragma unroll
        for (int nn = 0; nn < 4; ++nn)
            acc[m][nn] = (f32x4){0.f, 0.f, 0.f, 0.f};

    #pragma unroll
    for (int ks = 0; ks < 8; ++ks) {
        bf16x8 a[4], b[4];
        #pragma unroll
        for (int nn = 0; nn < 4; ++nn) {
            int c = wave * 64 + nn * 16 + r15;
            b[nn] = *(const bf16x8*)(Wt2 + ((size_t)(ks * 4 + kq) << 11) + (c << 3));
        }
        #pragma unroll
        for (int m = 0; m < 4; ++m) {
            int r = m * 16 + r15;
            a[m] = *(const bf16x8*)(sA + r * 512 + ((ks * 64 + kq * 16) ^ ((r & 7) << 4)));
        }
        #pragma unroll
        for (int m = 0; m < 4; ++m)
            #pragma unroll
            for (int nn = 0; nn < 4; ++nn)
                acc[m][nn] = __builtin_amdgcn_mfma_f32_16x16x32_bf16(a[m], b[nn], acc[m][nn], 0, 0, 0);
    }

    // epilogue: + gpart[seg], sigmoid, residual (LDS bf16) + g*nu
    #pragma unroll
    for (int m = 0; m < 4; ++m) {
        #pragma unroll
        for (int q = 0; q < 4; ++q) {
            int rr = m * 16 + kq * 4 + q;
            long node = (long)(i0 + rr);
            if (node >= n) continue;
            int bb = batch[node];
            #pragma unroll
            for (int nn = 0; nn < 4; ++nn) {
                int col = wave * 64 + nn * 16 + r15;
                float pre = acc[m][nn][q] + gpart[bb * DIM + col];
                float e = __expf(-pre);
                float gte = __builtin_amdgcn_rcpf(1.0f + e);
                float xres = __bfloat162float(
                    *(const __hip_bfloat16*)(sA + rr * 512 + ((2 * col) ^ ((rr & 7) << 4))));
                xout[(size_t)node * DIM + col] = xres + gte * nu[bb * DIM + col];
            }
        }
    }
}

// ---- Kernel 3b (fp32 fallback): reg-staged, BM=32 for high occupancy ---------
__global__ __launch_bounds__(256) void k_gate_fp(const float* __restrict__ x,
                                                 const int* __restrict__ batch,
                                                 const __hip_bfloat16* __restrict__ Wt2,
                                                 const float* __restrict__ nu,
                                                 const float* __restrict__ gpart,
                                                 float* __restrict__ xout,
                                                 int n) {
    __shared__ __align__(16) char sA[32 * 512];   // 16 KB bf16, swizzled

    const int tid  = threadIdx.x;
    const int wave = tid >> 6;
    const int lane = tid & 63;
    const int r15  = lane & 15;
    const int kq   = lane >> 4;
    const int i0   = blockIdx.x * 32;

    float4 av0[4], av1[4];
    #pragma unroll
    for (int j = 0; j < 4; ++j) {
        int v = j * 256 + tid;       // 0..1023
        int r = v >> 5;              // row 0..31
        int k8 = v & 31;
        int node = i0 + r;
        if (node < n) {
            const float* p = x + (size_t)node * DIM + k8 * 8;
            av0[j] = *(const float4*)p;
            av1[j] = *(const float4*)(p + 4);
        } else {
            av0[j] = make_float4(0.f, 0.f, 0.f, 0.f);
            av1[j] = av0[j];
        }
    }
    #pragma unroll
    for (int j = 0; j < 4; ++j) {
        int v = j * 256 + tid;
        int r = v >> 5;
        int k8 = v & 31;
        uint4 pk;
        pk.x = pack2bf(av0[j].x, av0[j].y);
        pk.y = pack2bf(av0[j].z, av0[j].w);
        pk.z = pack2bf(av1[j].x, av1[j].y);
        pk.w = pack2bf(av1[j].z, av1[j].w);
        *(uint4*)(sA + r * 512 + ((k8 * 16) ^ ((r & 7) << 4))) = pk;
    }
    __syncthreads();

    f32x4 acc[2][4];
    #pragma unroll
    for (int m = 0; m < 2; ++m)
        #pragma unroll
        for (int nn = 0; nn < 4; ++nn)
            acc[m][nn] = (f32x4){0.f, 0.f, 0.f, 0.f};

    #pragma unroll
    for (int ks = 0; ks < 8; ++ks) {
        bf16x8 a[2], b[4];
        #pragma unroll
        for (int nn = 0; nn < 4; ++nn) {
            int c = wave * 64 + nn * 16 + r15;
            b[nn] = *(const bf16x8*)(Wt2 + ((size_t)(ks * 4 + kq) << 11) + (c << 3));
        }
        #pragma unroll
        for (int m = 0; m < 2; ++m) {
            int r = m * 16 + r15;
            a[m] = *(const bf16x8*)(sA + r * 512 + ((ks * 64 + kq * 16) ^ ((r & 7) << 4)));
        }
        #pragma unroll
        for (int m = 0; m < 2; ++m)
            #pragma unroll
            for (int nn = 0; nn < 4; ++nn)
                acc[m][nn] = __builtin_amdgcn_mfma_f32_16x16x32_bf16(a[m], b[nn], acc[m][nn], 0, 0, 0);
    }

    #pragma unroll
    for (int m = 0; m < 2; ++m) {
        #pragma unroll
        for (int q = 0; q < 4; ++q) {
            int rr = m * 16 + kq * 4 + q;
            int node = i0 + rr;
            if (node >= n) continue;
            int bb = batch[node];
            #pragma unroll
            for (int nn = 0; nn < 4; ++nn) {
                int col = wave * 64 + nn * 16 + r15;
                float pre = acc[m][nn][q] + gpart[bb * DIM + col];
                float e = __expf(-pre);
                float gte = __builtin_amdgcn_rcpf(1.0f + e);
                float xres = __bfloat162float(
                    *(const __hip_bfloat16*)(sA + rr * 512 + ((2 * col) ^ ((rr & 7) << 4))));
                xout[(size_t)node * DIM + col] = xres + gte * nu[bb * DIM + col];
            }
        }
    }
}

extern "C" void kernel_launch(void* const* d_in, const int* in_sizes, int n_in,
                              void* d_out, int out_size, void* d_ws, size_t ws_size,
                              hipStream_t stream) {
    const float* x        = (const float*)d_in[0];
    const int*   batch    = (const int*)d_in[1];
    const float* vn_embed = (const float*)d_in[2];
    const float* W1  = (const float*)d_in[3];
    const float* b1  = (const float*)d_in[4];
    const float* g1  = (const float*)d_in[5];
    const float* be1 = (const float*)d_in[6];
    const float* W2  = (const float*)d_in[7];
    const float* b2  = (const float*)d_in[8];
    const float* g2  = (const float*)d_in[9];
    const float* be2 = (const float*)d_in[10];
    const float* Wg  = (const float*)d_in[11];
    const float* bg  = (const float*)d_in[12];

    const int n = in_sizes[0] / DIM;

    float* out = (float*)d_out;
    float* xout = out;                              // [N,D]
    float* vn_state_out = out + (size_t)n * DIM;    // [B,D]

    float* ws    = (float*)d_ws;
    float* sums  = ws;                                   // B*D
    float* cnt   = sums + (size_t)B_SEG * DIM;           // B
    float* nu    = cnt + B_SEG;                          // B*D
    float* gpart = nu + (size_t)B_SEG * DIM;             // B*D
    __hip_bfloat16* Wt2 = (__hip_bfloat16*)(gpart + (size_t)B_SEG * DIM); // 64K bf16
    __hip_bfloat16* xbf = Wt2 + (size_t)DIM * DIM;       // [ntile64*64][256] bf16

    const size_t base_bytes = ((size_t)B_SEG * DIM * 3 + B_SEG) * 4 + (size_t)DIM * DIM * 2;
    const int nt64 = (n + 63) / 64;
    const size_t need = base_bytes + (size_t)nt64 * 64 * 512;
    const bool use_bf = (ws_size >= need);

    hipMemsetAsync(d_ws, 0, ((size_t)B_SEG * DIM + B_SEG) * sizeof(float), stream);

    k_wprep<<<DIM, DIM, 0, stream>>>(Wg, Wt2);

    int nblk1 = (n + CHUNK - 1) / CHUNK;
    k_segsum<<<nblk1, 256, 0, stream>>>(x, batch, sums, cnt, xbf, n, use_bf ? 1 : 0);

    k_vn<<<B_SEG, 256, 0, stream>>>(sums, cnt, vn_embed,
                                    W1, b1, g1, be1,
                                    W2, b2, g2, be2,
                                    Wg, bg,
                                    vn_state_out, nu, gpart);

    if (use_bf) {
        k_gate_bf<<<nt64, 256, 0, stream>>>(xbf, batch, Wt2, nu, gpart, xout, n);
    } else {
        int nblk3 = (n + 31) / 32;
        k_gate_fp<<<nblk3, 256, 0, stream>>>(x, batch, Wt2, nu, gpart, xout, n);
    }
}